// Round 5
// baseline (895.305 us; speedup 1.0000x reference)
//
#include <hip/hip_runtime.h>

// Problem constants (from reference setup_inputs)
constexpr int Bsz   = 1024;     // batch
constexpr int F0    = 20000;    // input features
constexpr int NOUT0 = 5000, NOUT1 = 1000, NOUT2 = 256;
constexpr int NE0   = 100000, NE1 = 50000, NE2 = 10000;
constexpr int CNT_N  = NOUT0 + NOUT1 + NOUT2;   // 6256
constexpr int NE_TOT = NE0 + NE1 + NE2;         // 160000
constexpr int NT     = 1024;    // threads in fused kernel

// ---------------------------------------------------------------------------
// cnt[j] = in-degree of node j (all three layers concatenated) — feeds make_g.
__global__ __launch_bounds__(256) void count_edges(
    const int* __restrict__ dst0, const int* __restrict__ dst1,
    const int* __restrict__ dst2, int* __restrict__ cnt)
{
    const int i = blockIdx.x * 256 + threadIdx.x;
    if (i < NE0)                 atomicAdd(&cnt[dst0[i]], 1);
    else if (i < NE0 + NE1)      atomicAdd(&cnt[NOUT0 + dst1[i - NE0]], 1);
    else if (i < NE_TOT)         atomicAdd(&cnt[NOUT0 + NOUT1 + dst2[i - NE0 - NE1]], 1);
}

// pack[i] = src | (dst << 15)  — original (unsorted) edge order.
// src < 20000 < 2^15 and dst < 5000 < 2^13 for every layer, so this fits.
__global__ __launch_bounds__(256) void pack_build(
    const int* __restrict__ src0, const int* __restrict__ dst0,
    const int* __restrict__ src1, const int* __restrict__ dst1,
    const int* __restrict__ src2, const int* __restrict__ dst2,
    unsigned int* __restrict__ pack)
{
    const int i = blockIdx.x * 256 + threadIdx.x;
    if (i >= NE_TOT) return;
    unsigned s, d;
    if (i < NE0)            { s = (unsigned)src0[i];            d = (unsigned)dst0[i]; }
    else if (i < NE0 + NE1) { const int k = i - NE0;            s = (unsigned)src1[k]; d = (unsigned)dst1[k]; }
    else                    { const int k = i - NE0 - NE1;      s = (unsigned)src2[k]; d = (unsigned)dst2[k]; }
    pack[i] = s | (d << 15);
}

// g[j] = (1/max(cnt,1)) * pnext[j]  (pnext fused; 1.0 for last layer)
__global__ __launch_bounds__(256) void make_g(
    const int* __restrict__ cnt, const float* __restrict__ p1,
    const float* __restrict__ p2, float* __restrict__ g)
{
    const int j = blockIdx.x * 256 + threadIdx.x;
    if (j >= CNT_N) return;
    const float inv = 1.0f / fmaxf((float)cnt[j], 1.0f);
    float pn = 1.0f;
    if (j < NOUT0) pn = p1[j];
    else if (j < NOUT0 + NOUT1) pn = p2[j - NOUT0];
    g[j] = inv * pn;
}

// ---------------------------------------------------------------------------
// Fused per-batch-row network: one block = one batch row, all state in LDS.
// Walks are edge-parallel, branch-free, fully independent iterations:
//   pack load (coalesced) -> extract -> ds_read x[s] -> ds_add y[d].
__global__ __launch_bounds__(NT, 1) void fused_gnn(
    const float* __restrict__ data, const float* __restrict__ p0,
    const unsigned int* __restrict__ pack, const float* __restrict__ g,
    const float* __restrict__ W, const float* __restrict__ bias,
    float* __restrict__ out)
{
    __shared__ float x0s[F0];      // 80000 B
    __shared__ float y0s[NOUT0];   // 20000 B
    __shared__ float y1s[NOUT1];   //  4000 B
    __shared__ float y2s[NOUT2];   //  1024 B

    const int b = blockIdx.x;
    const int t = threadIdx.x;

    // Phase A: x0 = data[b] * p0 (float4), zero accumulators
    {
        const float4* __restrict__ dr = (const float4*)(data + (size_t)b * F0);
        const float4* __restrict__ pr = (const float4*)p0;
        float4* xr = (float4*)x0s;
#pragma unroll
        for (int i = 0; i < 5; ++i) {           // 5*1024 >= F0/4 = 5000
            const int idx = t + i * NT;
            if (idx < F0 / 4) {
                const float4 dv = dr[idx];
                const float4 pv = pr[idx];
                xr[idx] = make_float4(dv.x * pv.x, dv.y * pv.y, dv.z * pv.z, dv.w * pv.w);
            }
        }
    }
    for (int i = t; i < NOUT0; i += NT) y0s[i] = 0.f;
    if (t < NOUT1) y1s[t] = 0.f;
    if (t < NOUT2) y2s[t] = 0.f;
    __syncthreads();

    // Layer 0: 100k edges, edge-parallel
#pragma unroll 4
    for (int e = t; e < NE0; e += NT) {
        const unsigned w = pack[e];
        atomicAdd(&y0s[w >> 15], x0s[w & 0x7FFFu]);
    }
    __syncthreads();
    for (int i = t; i < NOUT0; i += NT) y0s[i] = fmaxf(y0s[i], 0.f) * g[i];
    __syncthreads();

    // Layer 1: 50k edges
#pragma unroll 4
    for (int e = t; e < NE1; e += NT) {
        const unsigned w = pack[NE0 + e];
        atomicAdd(&y1s[w >> 15], y0s[w & 0x7FFFu]);
    }
    __syncthreads();
    if (t < NOUT1) y1s[t] = fmaxf(y1s[t], 0.f) * g[NOUT0 + t];
    __syncthreads();

    // Layer 2: 10k edges
#pragma unroll 4
    for (int e = t; e < NE2; e += NT) {
        const unsigned w = pack[NE0 + NE1 + e];
        atomicAdd(&y2s[w >> 15], y1s[w & 0x7FFFu]);
    }
    __syncthreads();
    if (t < NOUT2) y2s[t] = fmaxf(y2s[t], 0.f) * g[NOUT0 + NOUT1 + t];
    __syncthreads();

    // Head: wave o (o<10) computes out[b][o] = dot(y2, W[o]) + bias[o]
    const int wid = t >> 6, lane = t & 63;
    if (wid < 10) {
        const float4 w4 = ((const float4*)(W + wid * 256))[lane];
        const float4 v4 = ((const float4*)y2s)[lane];
        float s = w4.x * v4.x + w4.y * v4.y + w4.z * v4.z + w4.w * v4.w;
#pragma unroll
        for (int off = 32; off > 0; off >>= 1) s += __shfl_xor(s, off);
        if (lane == 0) out[(size_t)b * 10 + wid] = s + bias[wid];
    }
}

// ---------------------------------------------------------------------------
extern "C" void kernel_launch(void* const* d_in, const int* in_sizes, int n_in,
                              void* d_out, int out_size, void* d_ws, size_t ws_size,
                              hipStream_t stream)
{
    const float* data = (const float*)d_in[0];
    const float* p0   = (const float*)d_in[1];
    const float* p1   = (const float*)d_in[2];
    const float* p2   = (const float*)d_in[3];
    const float* W    = (const float*)d_in[4];
    const float* bias = (const float*)d_in[5];
    const int* src0 = (const int*)d_in[6];
    const int* dst0 = (const int*)d_in[7];
    const int* src1 = (const int*)d_in[8];
    const int* dst1 = (const int*)d_in[9];
    const int* src2 = (const int*)d_in[10];
    const int* dst2 = (const int*)d_in[11];

    char* ws = (char*)d_ws;
    auto align = [](size_t x) { return (x + 255) & ~size_t(255); };
    size_t o = 0;
    int* cnt           = (int*)(ws + o);          o = align(o + (size_t)CNT_N * 4);
    unsigned int* pack = (unsigned int*)(ws + o); o = align(o + (size_t)NE_TOT * 4);
    float* g           = (float*)(ws + o);        o = align(o + (size_t)CNT_N * 4);

    hipMemsetAsync(cnt, 0, (size_t)CNT_N * 4, stream);

    count_edges<<<(NE_TOT + 255) / 256, 256, 0, stream>>>(dst0, dst1, dst2, cnt);
    pack_build<<<(NE_TOT + 255) / 256, 256, 0, stream>>>(
        src0, dst0, src1, dst1, src2, dst2, pack);
    make_g<<<(CNT_N + 255) / 256, 256, 0, stream>>>(cnt, p1, p2, g);

    fused_gnn<<<Bsz, NT, 0, stream>>>(data, p0, pack, g, W, bias, (float*)d_out);
}